// Round 12
// baseline (269.572 us; speedup 1.0000x reference)
//
#include <hip/hip_runtime.h>
#include <hip/hip_bf16.h>
#include <cstdint>

#define B_SZ 2048
#define T_SZ 512
#define F_SZ 64
#define BPB  4              // batch rows per block
#define TCH  32             // timesteps per chunk
#define NCHK (T_SZ / TCH)   // 16
#define NBLK (B_SZ / BPB)   // 512 -> 2 blocks/CU
#define NTHR 256            // wv0 scan, wv1 MFMA, wv2-3 staging
#define ROWS (BPB * TCH)    // 128 rows (b,t) per chunk
#define MT   (ROWS / 16)    // 8 M-tiles
#define NPC  (ROWS * 16)    // 2048 float4 staging pieces per chunk
#define NSTG 128            // staging threads (wv2+wv3)
#define PPT  (NPC / NSTG)   // 16 pieces per staging thread
#define TSTR 84             // zbuf t-stride (floats)
#define ESTR 20             // zbuf b-elem stride (floats)

typedef __attribute__((ext_vector_type(8))) short short8;
typedef __attribute__((ext_vector_type(4))) float f32x4;

__device__ __forceinline__ float fast_rcp(float x) { return __builtin_amdgcn_rcpf(x); }

// Eigen-style rational tanh (float): |err| ~1e-6 inside clamp, exact saturation feel
__device__ __forceinline__ float tanh_r(float xx) {
    const float xc = __builtin_amdgcn_fmed3f(xx, -7.90531110763549805f, 7.90531110763549805f);
    const float u  = xc * xc;
    float p = fmaf(u, -2.76076847742355e-16f, 2.00018790482477e-13f);
    p = fmaf(u, p, -8.60467152213735e-11f);
    p = fmaf(u, p,  5.12229709037114e-08f);
    p = fmaf(u, p,  1.48572235717979e-05f);
    p = fmaf(u, p,  6.37261928875436e-04f);
    p = fmaf(u, p,  4.89352455891786e-03f);
    p = p * xc;
    float qd = fmaf(u, 1.19825839466702e-06f, 1.18534705686654e-04f);
    qd = fmaf(u, qd, 2.26843463243900e-03f);
    qd = fmaf(u, qd, 4.89352518554385e-03f);
    return p * fast_rcp(qd);
}
// sigmoid(z) where zh = z/2 is already provided
__device__ __forceinline__ float sigm_h(float zh) { return fmaf(0.5f, tanh_r(zh), 0.5f); }

__device__ __forceinline__ unsigned short f2bf(float f) {
    __hip_bfloat16 h = (__hip_bfloat16)f;   // RNE
    return *reinterpret_cast<unsigned short*>(&h);
}

template<int CTRL>
__device__ __forceinline__ float qperm(float v) {
    return __int_as_float(__builtin_amdgcn_mov_dpp(__float_as_int(v), CTRL, 0xF, 0xF, false));
}
#define QPA 9    // lane k <- src[{1,2,0,0}[k]]  -> h_{(m+1)%3}
#define QPB 82   // lane k <- src[{2,0,1,1}[k]]  -> h_{(m+2)%3}

__global__ __launch_bounds__(NTHR) void lstm_mfma(const float* __restrict__ x,
                                                  const float* __restrict__ W,
                                                  const float* __restrict__ U,
                                                  const float* __restrict__ bias,
                                                  const float* __restrict__ Wd,
                                                  const float* __restrict__ bdp,
                                                  float* __restrict__ out) {
    // ring-3 A-fragment x (bf16) + double-buffered z
    __shared__ unsigned int xfrag[3][MT * 2 * 256];   // 3 x 16 KB
    __shared__ float zbuf[2][TCH * TSTR];             // 2 x 10.75 KB

    const int tid = threadIdx.x;
    const int wv  = tid >> 6;
    const int ln  = tid & 63;
    const int b0  = blockIdx.x * BPB;

    // ---- gate mapping: MFMA col n = gate p = mm*4+q  <-  W col q*3+mm ----
    // sigmoid gates (q=0,1,3) pre-scaled by 0.5 (sigmoid via tanh(z/2)); g-gate (q=2) natural
    const int n  = ln & 15;
    const int q  = n & 3, mm = n >> 2;
    const float sc = (q == 2) ? 1.0f : 0.5f;

    // ---- B-fragments: W stationary in VGPRs (wv1 only) ----
    short8 bfrag[2];
    #pragma unroll
    for (int kt = 0; kt < 2; ++kt) {
        short8 s;
        #pragma unroll
        for (int e = 0; e < 8; ++e) {
            const int hh = e >> 2, j = e & 3;
            const int kk = kt * 32 + hh * 16 + 4 * (ln >> 4) + j;   // f index
            const float w = (n < 12 && wv == 1) ? W[kk * 12 + q * 3 + mm] * sc : 0.0f;
            s[e] = (short)f2bf(w);
        }
        bfrag[kt] = s;
    }
    const float bias_s = (n < 12) ? bias[q * 3 + mm] * sc : 0.0f;

    // ---- scan constants (wv0; lanes 0..15: elems 0..3, one chain per lane) ----
    const int lk = ln & 3;
    const int m  = (lk < 3) ? lk : 2;
    const int mn = (m + 1 == 3) ? 0 : m + 1;
    const int mp = (m + 2 >= 3) ? m - 1 : m + 2;
    const int e8 = (ln >> 2) & 3;           // batch elem 0..3
    float u_own[4], u_nxt[4], u_prv[4];
    #pragma unroll
    for (int qq = 0; qq < 4; ++qq) {
        const float scq = (qq == 2) ? 1.0f : 0.5f;
        const int col = qq * 3 + m;
        u_own[qq] = U[m  * 12 + col] * scq;
        u_nxt[qq] = U[mn * 12 + col] * scq;
        u_prv[qq] = U[mp * 12 + col] * scq;
    }
    float h = 0.f, cc = 0.f, hA = 0.f, hB = 0.f;

    auto comp = [&](const float4& z4) {
        const float z0 = fmaf(h, u_own[0], z4.x) + fmaf(hA, u_nxt[0], hB * u_prv[0]);
        const float z1 = fmaf(h, u_own[1], z4.y) + fmaf(hA, u_nxt[1], hB * u_prv[1]);
        const float z2 = fmaf(h, u_own[2], z4.z) + fmaf(hA, u_nxt[2], hB * u_prv[2]);
        const float z3 = fmaf(h, u_own[3], z4.w) + fmaf(hA, u_nxt[3], hB * u_prv[3]);
        const float ai = sigm_h(z0);
        const float af = sigm_h(z1);
        const float ag = tanh_r(z2);
        const float ao = sigm_h(z3);
        cc = fmaf(af, cc, ai * ag);
        h = ao * tanh_r(cc);
        hA = qperm<QPA>(h);
        hB = qperm<QPB>(h);
    };

    auto scan32 = [&](const float* zb) {
        const float* zp = zb + e8 * ESTR + m * 4;
        float4 pf[8];
        #pragma unroll
        for (int i = 0; i < 8; ++i)
            pf[i] = *reinterpret_cast<const float4*>(zp + i * TSTR);
        __builtin_amdgcn_s_setprio(1);
        #pragma unroll 8
        for (int tt = 0; tt < TCH - 8; ++tt) {       // 24 iters, unconditional prefetch
            const float4 z4 = pf[tt & 7];
            pf[tt & 7] = *reinterpret_cast<const float4*>(zp + (tt + 8) * TSTR);
            comp(z4);
        }
        #pragma unroll
        for (int tt = TCH - 8; tt < TCH; ++tt)       // drain, static indices
            comp(pf[tt & 7]);
        __builtin_amdgcn_s_setprio(0);
    };

    // ---- staging (wv2-3): issue 2 chunks ahead; write lags 1 -> vmcnt wait ~ free ----
    float4 v[PPT];
    const int stid = tid - 128;             // 0..127 for wv2-3
    auto stage_issue = [&](int ck) {
        const int t0 = ck * TCH;
        #pragma unroll
        for (int i = 0; i < PPT; ++i) {
            const int piece = i * NSTG + stid;
            const int row = piece >> 4, g = piece & 15;
            v[i] = *reinterpret_cast<const float4*>(
                x + ((size_t)(b0 + (row >> 5)) * T_SZ + (t0 + (row & 31))) * F_SZ + (g << 2));
        }
    };
    auto stage_write = [&](int buf) {
        #pragma unroll
        for (int i = 0; i < PPT; ++i) {
            const int piece = i * NSTG + stid;
            const int row = piece >> 4, g = piece & 15;
            const int u_off = ((row >> 4) * 2 + (g >> 3)) * 256
                            + (((row & 15) | ((g & 3) << 4)) << 2) + ((g >> 2) & 1) * 2;
            uint2 pk;
            pk.x = (unsigned)f2bf(v[i].x) | ((unsigned)f2bf(v[i].y) << 16);
            pk.y = (unsigned)f2bf(v[i].z) | ((unsigned)f2bf(v[i].w) << 16);
            *reinterpret_cast<uint2*>(&xfrag[buf][u_off]) = pk;
        }
    };

    auto mfma_chunk = [&](int buf, int zb) {
        #pragma unroll
        for (int mt = 0; mt < MT; ++mt) {
            f32x4 acc = { bias_s, bias_s, bias_s, bias_s };
            const short8 a0 = *reinterpret_cast<const short8*>(&xfrag[buf][(mt * 2 + 0) * 256 + (ln << 2)]);
            const short8 a1 = *reinterpret_cast<const short8*>(&xfrag[buf][(mt * 2 + 1) * 256 + (ln << 2)]);
            acc = __builtin_amdgcn_mfma_f32_16x16x32_bf16(a0, bfrag[0], acc, 0, 0, 0);
            acc = __builtin_amdgcn_mfma_f32_16x16x32_bf16(a1, bfrag[1], acc, 0, 0, 0);
            const int rbase = mt * 16 + 4 * (ln >> 4);
            #pragma unroll
            for (int r = 0; r < 4; ++r) {
                const int rr = rbase + r;                 // row = b*32 + t
                zbuf[zb][(rr & 31) * TSTR + (rr >> 5) * ESTR + n] = acc[r];
            }
        }
    };

    // ---- prologue: chunk 0 staged, chunk 1 loads in flight ----
    if (wv >= 2) {
        stage_issue(0);
        stage_write(0);        // compiler-inserted vmcnt wait (once, prologue only)
        stage_issue(1);
    }
    __syncthreads();

    // ---- pipeline: write(k+1)+issue(k+2) || mfma z(k) || scan(k-1) ----
    for (int k = 0; k < NCHK; ++k) {
        if (wv >= 2) {
            if (k + 1 < NCHK) stage_write((k + 1) % 3);   // data issued at chunk k-1
            if (k + 2 < NCHK) stage_issue(k + 2);
        } else if (wv == 1) {
            mfma_chunk(k % 3, k & 1);
        } else if (k > 0) {
            scan32(zbuf[(k - 1) & 1]);
        }
        __syncthreads();
    }

    // ---- epilogue: scan last chunk + dense head (sigmoid via tanh) ----
    if (wv == 0) {
        scan32(zbuf[(NCHK - 1) & 1]);
        if (lk == 0 && ln < 16) {
            const float logit = bdp[0] + h * Wd[m] + hA * Wd[mn] + hB * Wd[mp];
            out[b0 + e8] = fmaf(0.5f, tanh_r(0.5f * logit), 0.5f);
        }
    }
}

extern "C" void kernel_launch(void* const* d_in, const int* in_sizes, int n_in,
                              void* d_out, int out_size, void* d_ws, size_t ws_size,
                              hipStream_t stream) {
    (void)in_sizes; (void)n_in; (void)out_size; (void)d_ws; (void)ws_size;
    const float* x  = (const float*)d_in[0];
    const float* W  = (const float*)d_in[1];
    const float* U  = (const float*)d_in[2];
    const float* b  = (const float*)d_in[3];
    const float* Wd = (const float*)d_in[4];
    const float* bd = (const float*)d_in[5];
    float* out = (float*)d_out;

    lstm_mfma<<<NBLK, NTHR, 0, stream>>>(x, W, U, b, Wd, bd, out);
}

// Round 13
// 73.290 us; speedup vs baseline: 3.6782x; 3.6782x over previous
//
#include <hip/hip_runtime.h>
#include <hip/hip_bf16.h>
#include <cstdint>

#define B_SZ 2048
#define T_SZ 512
#define F_SZ 64
#define BPB  4              // batch rows per block
#define TCH  32             // timesteps per chunk
#define NCHK (T_SZ / TCH)   // 16
#define NBLK (B_SZ / BPB)   // 512 -> 2 blocks/CU
#define NTHR 256            // wv0 scan, wv1 MFMA, wv2-3 staging
#define ROWS (BPB * TCH)    // 128 rows (b,t) per chunk
#define MT   (ROWS / 16)    // 8 M-tiles
#define NPC  (ROWS * 16)    // 2048 float4 staging pieces per chunk
#define NSTG 128            // staging threads (wv2+wv3)
#define PPT  (NPC / NSTG)   // 16 pieces per staging thread
#define TSTR 84             // zbuf t-stride (floats)
#define ESTR 20             // zbuf b-elem stride (floats)

#define L2E 1.4426950408889634f

typedef __attribute__((ext_vector_type(8))) short short8;
typedef __attribute__((ext_vector_type(4))) float f32x4;

__device__ __forceinline__ float fast_rcp(float x) { return __builtin_amdgcn_rcpf(x); }
__device__ __forceinline__ float exp2h(float x)    { return __builtin_amdgcn_exp2f(x); }
__device__ __forceinline__ float sigm_s(float zs)  { return fast_rcp(1.0f + exp2h(zs)); }
__device__ __forceinline__ float sigm_n(float x)   { return sigm_s(x * (-L2E)); }

// Estrin-scheduled rational tanh (Eigen coefficients), natural argument.
// Depth ~20 cy + one rcp; 15 VALU ops. |err| ~1e-6; clamp handles saturation.
__device__ __forceinline__ float tanh_e(float xx) {
    const float xc = __builtin_amdgcn_fmed3f(xx, -7.90531110763549805f, 7.90531110763549805f);
    const float u  = xc * xc;
    const float u2 = u * u;
    const float u4 = u2 * u2;
    const float t0 = fmaf(u, 6.37261928875436e-04f, 4.89352455891786e-03f);
    const float t1 = fmaf(u, 5.12229709037114e-08f, 1.48572235717979e-05f);
    const float t2 = fmaf(u, 2.00018790482477e-13f, -8.60467152213735e-11f);
    const float s0 = fmaf(u2, t1, t0);
    const float s1 = fmaf(u2, -2.76076847742355e-16f, t2);
    const float pn = fmaf(u4, s1, s0) * xc;
    const float q0 = fmaf(u, 2.26843463243900e-03f, 4.89352518554385e-03f);
    const float q1 = fmaf(u, 1.19825839466702e-06f, 1.18534705686654e-04f);
    const float qd = fmaf(u2, q1, q0);
    return pn * fast_rcp(qd);
}

__device__ __forceinline__ unsigned short f2bf(float f) {
    __hip_bfloat16 h = (__hip_bfloat16)f;   // RNE
    return *reinterpret_cast<unsigned short*>(&h);
}

template<int CTRL>
__device__ __forceinline__ float qperm(float v) {
    return __int_as_float(__builtin_amdgcn_mov_dpp(__float_as_int(v), CTRL, 0xF, 0xF, false));
}
#define QPA 9    // lane k <- src[{1,2,0,0}[k]]  -> h_{(m+1)%3}
#define QPB 82   // lane k <- src[{2,0,1,1}[k]]  -> h_{(m+2)%3}

__global__ __launch_bounds__(NTHR) void lstm_mfma(const float* __restrict__ x,
                                                  const float* __restrict__ W,
                                                  const float* __restrict__ U,
                                                  const float* __restrict__ bias,
                                                  const float* __restrict__ Wd,
                                                  const float* __restrict__ bdp,
                                                  float* __restrict__ out) {
    // A-fragment-ordered x (bf16): per (Mtile,Ktile): 64 lanes x 16B
    __shared__ unsigned int xfrag[2][MT * 2 * 256];   // 2 x 16 KB
    __shared__ float zbuf[2][TCH * TSTR];             // 2 x 10.75 KB

    const int tid = threadIdx.x;
    const int wv  = tid >> 6;
    const int ln  = tid & 63;
    const int b0  = blockIdx.x * BPB;

    // ---- per-lane gate mapping (gate p = mm*4+q <- W col q*3+mm), scaled ----
    const int n  = ln & 15;                 // MFMA col = gate index (12 real + 4 pad)
    const int q  = n & 3, mm = n >> 2;
    const float sc = (q == 2) ? (-2.0f * L2E) : (-L2E);

    // ---- B-fragments: W stationary in VGPRs (wv1 only uses them) ----
    short8 bfrag[2];
    #pragma unroll
    for (int kt = 0; kt < 2; ++kt) {
        short8 s;
        #pragma unroll
        for (int e = 0; e < 8; ++e) {
            const int hh = e >> 2, j = e & 3;
            const int kk = kt * 32 + hh * 16 + 4 * (ln >> 4) + j;   // f index
            const float w = (n < 12 && wv == 1) ? W[kk * 12 + q * 3 + mm] * sc : 0.0f;
            s[e] = (short)f2bf(w);
        }
        bfrag[kt] = s;
    }
    const float bias_s = (n < 12) ? bias[q * 3 + mm] * sc : 0.0f;

    // ---- scan constants (wv0; lanes 0..15: elems 0..3, one chain per lane) ----
    const int lk = ln & 3;
    const int m  = (lk < 3) ? lk : 2;
    const int mn = (m + 1 == 3) ? 0 : m + 1;
    const int mp = (m + 2 >= 3) ? m - 1 : m + 2;
    const int e8 = (ln >> 2) & 3;           // batch elem 0..3
    float u_own[4], u_nxt[4], u_prv[4];
    #pragma unroll
    for (int qq = 0; qq < 4; ++qq) {
        const float scq = (qq == 2) ? (-2.0f * L2E) : (-L2E);
        const int col = qq * 3 + m;
        u_own[qq] = U[m  * 12 + col] * scq;
        u_nxt[qq] = U[mn * 12 + col] * scq;
        u_prv[qq] = U[mp * 12 + col] * scq;
    }
    // state: h natural, cc natural, hA/hB quad-neighbors' h
    float h = 0.f, cc = 0.f, hA = 0.f, hB = 0.f;

    auto comp = [&](const float4& z4) {
        const float z0 = fmaf(h, u_own[0], z4.x) + fmaf(hA, u_nxt[0], hB * u_prv[0]);
        const float z1 = fmaf(h, u_own[1], z4.y) + fmaf(hA, u_nxt[1], hB * u_prv[1]);
        const float z2 = fmaf(h, u_own[2], z4.z) + fmaf(hA, u_nxt[2], hB * u_prv[2]);
        const float z3 = fmaf(h, u_own[3], z4.w) + fmaf(hA, u_nxt[3], hB * u_prv[3]);
        const float ai = sigm_s(z0);                                  // exp2 form (proven)
        const float af = sigm_s(z1);
        const float ag = fmaf(2.0f, fast_rcp(1.0f + exp2h(z2)), -1.0f);  // tanh, scaled z2
        const float ao = sigm_s(z3);
        cc = fmaf(af, cc, ai * ag);
        h = ao * tanh_e(cc);                                          // SINGLE-AXIS CHANGE
        hA = qperm<QPA>(h);
        hB = qperm<QPB>(h);
    };

    auto scan32 = [&](const float* zb) {
        const float* zp = zb + e8 * ESTR + m * 4;
        float4 pf[8];
        #pragma unroll
        for (int i = 0; i < 8; ++i)
            pf[i] = *reinterpret_cast<const float4*>(zp + i * TSTR);
        __builtin_amdgcn_s_setprio(1);
        #pragma unroll
        for (int tt = 0; tt < TCH; ++tt) {           // static unroll -> pf in regs
            const float4 z4 = pf[tt & 7];
            if (tt + 8 < TCH)
                pf[tt & 7] = *reinterpret_cast<const float4*>(zp + (tt + 8) * TSTR);
            comp(z4);
        }
        __builtin_amdgcn_s_setprio(0);
    };

    // ---- staging (wv2-3 only): issue-early global loads, convert+write bf16 A-frags ----
    float4 v[PPT];
    const int stid = tid - 128;             // 0..127 for wv2-3
    auto stage_issue = [&](int ck) {
        const int t0 = ck * TCH;
        #pragma unroll
        for (int i = 0; i < PPT; ++i) {
            const int piece = i * NSTG + stid;
            const int row = piece >> 4, g = piece & 15;
            v[i] = *reinterpret_cast<const float4*>(
                x + ((size_t)(b0 + (row >> 5)) * T_SZ + (t0 + (row & 31))) * F_SZ + (g << 2));
        }
    };
    auto stage_write = [&](int buf) {
        #pragma unroll
        for (int i = 0; i < PPT; ++i) {
            const int piece = i * NSTG + stid;
            const int row = piece >> 4, g = piece & 15;
            const int u_off = ((row >> 4) * 2 + (g >> 3)) * 256
                            + (((row & 15) | ((g & 3) << 4)) << 2) + ((g >> 2) & 1) * 2;
            uint2 pk;
            pk.x = (unsigned)f2bf(v[i].x) | ((unsigned)f2bf(v[i].y) << 16);
            pk.y = (unsigned)f2bf(v[i].z) | ((unsigned)f2bf(v[i].w) << 16);
            *reinterpret_cast<uint2*>(&xfrag[buf][u_off]) = pk;
        }
    };

    auto mfma_chunk = [&](int cur) {
        #pragma unroll
        for (int mt = 0; mt < MT; ++mt) {
            f32x4 acc = { bias_s, bias_s, bias_s, bias_s };
            const short8 a0 = *reinterpret_cast<const short8*>(&xfrag[cur][(mt * 2 + 0) * 256 + (ln << 2)]);
            const short8 a1 = *reinterpret_cast<const short8*>(&xfrag[cur][(mt * 2 + 1) * 256 + (ln << 2)]);
            acc = __builtin_amdgcn_mfma_f32_16x16x32_bf16(a0, bfrag[0], acc, 0, 0, 0);
            acc = __builtin_amdgcn_mfma_f32_16x16x32_bf16(a1, bfrag[1], acc, 0, 0, 0);
            const int rbase = mt * 16 + 4 * (ln >> 4);
            #pragma unroll
            for (int r = 0; r < 4; ++r) {
                const int rr = rbase + r;                 // row = b*32 + t
                zbuf[cur][(rr & 31) * TSTR + (rr >> 5) * ESTR + n] = acc[r];
            }
        }
    };

    // ---- prologue: staging waves fill chunk 0 ----
    if (wv >= 2) { stage_issue(0); stage_write(0); }
    __syncthreads();

    // ---- pipeline: staging(k+1) || mfma z(k) || scan(k-1), one barrier/chunk ----
    for (int k = 0; k < NCHK; ++k) {
        const int cur = k & 1;
        if (wv >= 2) {
            if (k + 1 < NCHK) { stage_issue(k + 1); stage_write(cur ^ 1); }
        } else if (wv == 1) {
            mfma_chunk(cur);
        } else if (k > 0) {
            scan32(zbuf[cur ^ 1]);
        }
        __syncthreads();
    }

    // ---- epilogue: scan last chunk + dense head ----
    if (wv == 0) {
        scan32(zbuf[(NCHK - 1) & 1]);
        if (lk == 0 && ln < 16) {
            const float logit = bdp[0] + h * Wd[m] + hA * Wd[mn] + hB * Wd[mp];
            out[b0 + e8] = sigm_n(logit);
        }
    }
}

extern "C" void kernel_launch(void* const* d_in, const int* in_sizes, int n_in,
                              void* d_out, int out_size, void* d_ws, size_t ws_size,
                              hipStream_t stream) {
    (void)in_sizes; (void)n_in; (void)out_size; (void)d_ws; (void)ws_size;
    const float* x  = (const float*)d_in[0];
    const float* W  = (const float*)d_in[1];
    const float* U  = (const float*)d_in[2];
    const float* b  = (const float*)d_in[3];
    const float* Wd = (const float*)d_in[4];
    const float* bd = (const float*)d_in[5];
    float* out = (float*)d_out;

    lstm_mfma<<<NBLK, NTHR, 0, stream>>>(x, W, U, b, Wd, bd, out);
}

// Round 15
// 64.211 us; speedup vs baseline: 4.1982x; 1.1414x over previous
//
#include <hip/hip_runtime.h>
#include <hip/hip_bf16.h>
#include <cstdint>

#define B_SZ 2048
#define T_SZ 512
#define F_SZ 64
#define BPB  4              // batch rows per block
#define TCH  32             // timesteps per chunk
#define NCHK (T_SZ / TCH)   // 16
#define NBLK (B_SZ / BPB)   // 512 -> 2 blocks/CU
#define NTHR 256            // wv0 scan, wv1 MFMA, wv2-3 staging
#define ROWS (BPB * TCH)    // 128 rows (b,t) per chunk
#define MT   (ROWS / 16)    // 8 M-tiles
#define NPC  (ROWS * 16)    // 2048 float4 staging pieces per chunk
#define NSTG 128            // staging threads (wv2+wv3)
#define PPT  (NPC / NSTG)   // 16 pieces per staging thread
#define TSTR 84             // zbuf t-stride (floats)
#define ESTR 20             // zbuf b-elem stride (floats)

#define L2E 1.4426950408889634f

typedef __attribute__((ext_vector_type(8))) short short8;
typedef __attribute__((ext_vector_type(4))) float f32x4;

__device__ __forceinline__ float fast_rcp(float x) { return __builtin_amdgcn_rcpf(x); }
__device__ __forceinline__ float exp2h(float x)    { return __builtin_amdgcn_exp2f(x); }
__device__ __forceinline__ float sigm_s(float zs)  { return fast_rcp(1.0f + exp2h(zs)); }
__device__ __forceinline__ float sigm_n(float x)   { return sigm_s(x * (-L2E)); }

__device__ __forceinline__ unsigned short f2bf(float f) {
    __hip_bfloat16 h = (__hip_bfloat16)f;   // RNE
    return *reinterpret_cast<unsigned short*>(&h);
}

template<int CTRL>
__device__ __forceinline__ float dppmv(float v) {
    // bound_ctrl=true: out-of-row source reads 0 (keeps junk lanes bounded)
    return __int_as_float(__builtin_amdgcn_mov_dpp(__float_as_int(v), CTRL, 0xF, 0xF, true));
}
// DPP semantics (ISA): row_shr:N -> lane i reads lane i-N ; row_shl:N -> lane i reads lane i+N
#define DPP_SHR6 0x116   // i-gates: src lanes 0..2  -> dst 6..8
#define DPP_SHR3 0x113   // f-gates: src lanes 3..5  -> dst 6..8
#define DPP_SHL3 0x103   // o-gates: src lanes 9..11 -> dst 6..8

template<int OFF>
__device__ __forceinline__ float swz(float v) {
    return __int_as_float(__builtin_amdgcn_ds_swizzle(__float_as_int(v), OFF));
}
// BitMode offset = (xor<<10)|(or<<5)|and ; src lane = ((lane & and) | or) ^ xor  (per 32-lane group)
#define SWZ_B6 0x0D0   // and=0x10, or=6: each 16-lane row reads its lane 6
#define SWZ_B7 0x0F0   // or=7
#define SWZ_B8 0x110   // or=8

__global__ __launch_bounds__(NTHR) void lstm_mfma(const float* __restrict__ x,
                                                  const float* __restrict__ W,
                                                  const float* __restrict__ U,
                                                  const float* __restrict__ bias,
                                                  const float* __restrict__ Wd,
                                                  const float* __restrict__ bdp,
                                                  float* __restrict__ out) {
    // A-fragment-ordered x (bf16): per (Mtile,Ktile): 64 lanes x 16B
    __shared__ unsigned int xfrag[2][MT * 2 * 256];   // 2 x 16 KB
    __shared__ float zbuf[2][TCH * TSTR];             // 2 x 10.75 KB

    const int tid = threadIdx.x;
    const int wv  = tid >> 6;
    const int ln  = tid & 63;
    const int b0  = blockIdx.x * BPB;

    // ---- gate mapping: MFMA col n = Keras gate col (q*3+m), q=n/3, m=n%3 ----
    const int n  = ln & 15;                 // 12 real gates + 4 pad
    const int q  = n / 3;                   // 0:i 1:f 2:g 3:o (n<12)
    const float scq = (q == 2) ? (-2.0f * L2E) : (-L2E);

    // ---- B-fragments: W stationary in VGPRs (wv1 only uses them) ----
    short8 bfrag[2];
    #pragma unroll
    for (int kt = 0; kt < 2; ++kt) {
        short8 s;
        #pragma unroll
        for (int e = 0; e < 8; ++e) {
            const int hh = e >> 2, j = e & 3;
            const int kk = kt * 32 + hh * 16 + 4 * (ln >> 4) + j;   // f index
            const float w = (n < 12 && wv == 1) ? W[kk * 12 + n] * scq : 0.0f;
            s[e] = (short)f2bf(w);
        }
        bfrag[kt] = s;
    }
    const float bias_s = (n < 12) ? bias[n] * scq : 0.0f;

    // ---- scan constants (wv0): lane n = gate col; element e16 = ln>>4 ----
    const int e16 = ln >> 4;                // batch elem 0..3
    float u0 = 0.f, u1 = 0.f, u2 = 0.f, gA = 0.f, gB = 0.f;
    if (n < 12) {
        u0 = U[0 * 12 + n] * scq;
        u1 = U[1 * 12 + n] * scq;
        u2 = U[2 * 12 + n] * scq;
        if (q == 2) { gA = -4.0f * L2E; gB = 2.0f * L2E; }  // pre-scaled tanh: -2*L2E*tanh(z)
        else        { gA = 1.0f;        gB = 0.0f;       }  // sigmoid
    }
    // state: cs = -2*L2E*c (g-lanes 6..8 hold unit m=n-6); h broadcasts in h0b/h1b/h2b
    float cs = 0.f, h0b = 0.f, h1b = 0.f, h2b = 0.f;

    auto comp = [&](float z4) {
        const float z  = fmaf(h0b, u0, fmaf(h1b, u1, fmaf(h2b, u2, z4)));
        const float r  = fast_rcp(1.0f + exp2h(z));      // ONE exp2 + ONE rcp for all gates
        const float gt = fmaf(gA, r, gB);                // sigmoid / pre-scaled tanh
        const float iV = dppmv<DPP_SHR6>(gt);            // i: lanes 0..2  -> 6..8
        const float fV = dppmv<DPP_SHR3>(gt);            // f: lanes 3..5  -> 6..8
        const float oV = dppmv<DPP_SHL3>(gt);            // o: lanes 9..11 -> 6..8
        cs = fmaf(fV, cs, iV * gt);                      // g-lanes: gt = -2*L2E*g
        const float th = fmaf(2.0f, fast_rcp(1.0f + exp2h(cs)), -1.0f);  // tanh(c)
        const float h  = oV * th;                        // h_m on lane 6+m
        h0b = swz<SWZ_B6>(h);
        h1b = swz<SWZ_B7>(h);
        h2b = swz<SWZ_B8>(h);
    };

    auto scan32 = [&](const float* zb) {
        const float* zp = zb + e16 * ESTR + n;
        float pf[8];
        #pragma unroll
        for (int i = 0; i < 8; ++i) pf[i] = zp[i * TSTR];
        __builtin_amdgcn_s_setprio(1);
        #pragma unroll
        for (int tt = 0; tt < TCH; ++tt) {               // static unroll -> pf in regs
            const float z4 = pf[tt & 7];
            if (tt + 8 < TCH) pf[tt & 7] = zp[(tt + 8) * TSTR];
            comp(z4);
        }
        __builtin_amdgcn_s_setprio(0);
    };

    // ---- staging (wv2-3 only): issue-early global loads, convert+write bf16 A-frags ----
    float4 v[PPT];
    const int stid = tid - 128;             // 0..127 for wv2-3
    auto stage_issue = [&](int ck) {
        const int t0 = ck * TCH;
        #pragma unroll
        for (int i = 0; i < PPT; ++i) {
            const int piece = i * NSTG + stid;
            const int row = piece >> 4, g = piece & 15;
            v[i] = *reinterpret_cast<const float4*>(
                x + ((size_t)(b0 + (row >> 5)) * T_SZ + (t0 + (row & 31))) * F_SZ + (g << 2));
        }
    };
    auto stage_write = [&](int buf) {
        #pragma unroll
        for (int i = 0; i < PPT; ++i) {
            const int piece = i * NSTG + stid;
            const int row = piece >> 4, g = piece & 15;
            const int u_off = ((row >> 4) * 2 + (g >> 3)) * 256
                            + (((row & 15) | ((g & 3) << 4)) << 2) + ((g >> 2) & 1) * 2;
            uint2 pk;
            pk.x = (unsigned)f2bf(v[i].x) | ((unsigned)f2bf(v[i].y) << 16);
            pk.y = (unsigned)f2bf(v[i].z) | ((unsigned)f2bf(v[i].w) << 16);
            *reinterpret_cast<uint2*>(&xfrag[buf][u_off]) = pk;
        }
    };

    auto mfma_chunk = [&](int cur) {
        #pragma unroll
        for (int mt = 0; mt < MT; ++mt) {
            f32x4 acc = { bias_s, bias_s, bias_s, bias_s };
            const short8 a0 = *reinterpret_cast<const short8*>(&xfrag[cur][(mt * 2 + 0) * 256 + (ln << 2)]);
            const short8 a1 = *reinterpret_cast<const short8*>(&xfrag[cur][(mt * 2 + 1) * 256 + (ln << 2)]);
            acc = __builtin_amdgcn_mfma_f32_16x16x32_bf16(a0, bfrag[0], acc, 0, 0, 0);
            acc = __builtin_amdgcn_mfma_f32_16x16x32_bf16(a1, bfrag[1], acc, 0, 0, 0);
            const int rbase = mt * 16 + 4 * (ln >> 4);
            #pragma unroll
            for (int r = 0; r < 4; ++r) {
                const int rr = rbase + r;                 // row = b*32 + t
                zbuf[cur][(rr & 31) * TSTR + (rr >> 5) * ESTR + n] = acc[r];
            }
        }
    };

    // ---- prologue: staging waves fill chunk 0 ----
    if (wv >= 2) { stage_issue(0); stage_write(0); }
    __syncthreads();

    // ---- pipeline: staging(k+1) || mfma z(k) || scan(k-1), one barrier/chunk ----
    for (int k = 0; k < NCHK; ++k) {
        const int cur = k & 1;
        if (wv >= 2) {
            if (k + 1 < NCHK) { stage_issue(k + 1); stage_write(cur ^ 1); }
        } else if (wv == 1) {
            mfma_chunk(cur);
        } else if (k > 0) {
            scan32(zbuf[cur ^ 1]);
        }
        __syncthreads();
    }

    // ---- epilogue: scan last chunk + dense head ----
    if (wv == 0) {
        scan32(zbuf[(NCHK - 1) & 1]);
        if (n == 0) {   // one lane per element; h broadcasts hold h0,h1,h2
            const float logit = bdp[0] + h0b * Wd[0] + h1b * Wd[1] + h2b * Wd[2];
            out[b0 + e16] = sigm_n(logit);
        }
    }
}

extern "C" void kernel_launch(void* const* d_in, const int* in_sizes, int n_in,
                              void* d_out, int out_size, void* d_ws, size_t ws_size,
                              hipStream_t stream) {
    (void)in_sizes; (void)n_in; (void)out_size; (void)d_ws; (void)ws_size;
    const float* x  = (const float*)d_in[0];
    const float* W  = (const float*)d_in[1];
    const float* U  = (const float*)d_in[2];
    const float* b  = (const float*)d_in[3];
    const float* Wd = (const float*)d_in[4];
    const float* bd = (const float*)d_in[5];
    float* out = (float*)d_out;

    lstm_mfma<<<NBLK, NTHR, 0, stream>>>(x, W, U, b, Wd, bd, out);
}

// Round 16
// 54.190 us; speedup vs baseline: 4.9746x; 1.1849x over previous
//
#include <hip/hip_runtime.h>
#include <hip/hip_bf16.h>
#include <cstdint>

#define B_SZ 2048
#define T_SZ 512
#define F_SZ 64
#define BPB  4              // batch rows per block
#define TCH  32             // timesteps per chunk
#define NCHK (T_SZ / TCH)   // 16
#define NBLK (B_SZ / BPB)   // 512 -> 2 blocks/CU
#define NTHR 256            // wv0 scan, wv1 MFMA, wv2-3 staging
#define ROWS (BPB * TCH)    // 128 rows (b,t) per chunk
#define MT   (ROWS / 16)    // 8 M-tiles
#define NPC  (ROWS * 16)    // 2048 float4 staging pieces per chunk
#define NSTG 128            // staging threads (wv2+wv3)
#define PPT  (NPC / NSTG)   // 16 pieces per staging thread
#define TSTR 84             // zbuf t-stride (floats)
#define ESTR 20             // zbuf b-elem stride (floats)

#define L2E 1.4426950408889634f

typedef __attribute__((ext_vector_type(8))) short short8;
typedef __attribute__((ext_vector_type(4))) float f32x4;

__device__ __forceinline__ float fast_rcp(float x) { return __builtin_amdgcn_rcpf(x); }
__device__ __forceinline__ float exp2h(float x)    { return __builtin_amdgcn_exp2f(x); }
__device__ __forceinline__ float sigm_s(float zs)  { return fast_rcp(1.0f + exp2h(zs)); }
__device__ __forceinline__ float sigm_n(float x)   { return sigm_s(x * (-L2E)); }

__device__ __forceinline__ unsigned short f2bf(float f) {
    __hip_bfloat16 h = (__hip_bfloat16)f;   // RNE
    return *reinterpret_cast<unsigned short*>(&h);
}

template<int CTRL>
__device__ __forceinline__ float dppmv(float v) {
    // bound_ctrl=true: out-of-row source reads 0 (keeps junk lanes bounded)
    return __int_as_float(__builtin_amdgcn_mov_dpp(__float_as_int(v), CTRL, 0xF, 0xF, true));
}
// DPP semantics (ISA): row_shr:N -> lane i reads lane i-N ; row_shl:N -> lane i reads lane i+N
#define DPP_SHR6 0x116   // i-gates: src lanes 0..2  -> dst 6..8
#define DPP_SHR3 0x113   // f-gates: src lanes 3..5  -> dst 6..8
#define DPP_SHL3 0x103   // o-gates: src lanes 9..11 -> dst 6..8
// gfx90a+ row_newbcast:N (0x150+N): broadcast row-lane N to all 16 lanes of the row (VALU DPP)
#define DPP_NB6  0x156
#define DPP_NB7  0x157
#define DPP_NB8  0x158

__global__ __launch_bounds__(NTHR) void lstm_mfma(const float* __restrict__ x,
                                                  const float* __restrict__ W,
                                                  const float* __restrict__ U,
                                                  const float* __restrict__ bias,
                                                  const float* __restrict__ Wd,
                                                  const float* __restrict__ bdp,
                                                  float* __restrict__ out) {
    // A-fragment-ordered x (bf16): per (Mtile,Ktile): 64 lanes x 16B
    __shared__ unsigned int xfrag[2][MT * 2 * 256];   // 2 x 16 KB
    __shared__ float zbuf[2][TCH * TSTR];             // 2 x 10.75 KB

    const int tid = threadIdx.x;
    const int wv  = tid >> 6;
    const int ln  = tid & 63;
    const int b0  = blockIdx.x * BPB;

    // ---- gate mapping: MFMA col n = Keras gate col (q*3+m), q=n/3, m=n%3 ----
    const int n  = ln & 15;                 // 12 real gates + 4 pad
    const int q  = n / 3;                   // 0:i 1:f 2:g 3:o (n<12)
    const float scq = (q == 2) ? (-2.0f * L2E) : (-L2E);

    // ---- B-fragments: W stationary in VGPRs (wv1 only uses them) ----
    short8 bfrag[2];
    #pragma unroll
    for (int kt = 0; kt < 2; ++kt) {
        short8 s;
        #pragma unroll
        for (int e = 0; e < 8; ++e) {
            const int hh = e >> 2, j = e & 3;
            const int kk = kt * 32 + hh * 16 + 4 * (ln >> 4) + j;   // f index
            const float w = (n < 12 && wv == 1) ? W[kk * 12 + n] * scq : 0.0f;
            s[e] = (short)f2bf(w);
        }
        bfrag[kt] = s;
    }
    const float bias_s = (n < 12) ? bias[n] * scq : 0.0f;

    // ---- scan constants (wv0): lane n = gate col; element e16 = ln>>4 ----
    const int e16 = ln >> 4;                // batch elem 0..3
    float u0 = 0.f, u1 = 0.f, u2 = 0.f, gA = 0.f, gB = 0.f;
    if (n < 12) {
        u0 = U[0 * 12 + n] * scq;
        u1 = U[1 * 12 + n] * scq;
        u2 = U[2 * 12 + n] * scq;
        if (q == 2) { gA = -4.0f * L2E; gB = 2.0f * L2E; }  // pre-scaled tanh: -2*L2E*tanh(z)
        else        { gA = 1.0f;        gB = 0.0f;       }  // sigmoid
    }
    // state: cs = -2*L2E*c (g-lanes 6..8 hold unit m=n-6); h broadcasts in h0b/h1b/h2b
    float cs = 0.f, h0b = 0.f, h1b = 0.f, h2b = 0.f;

    auto comp = [&](float z4) {
        const float z  = fmaf(h0b, u0, fmaf(h1b, u1, fmaf(h2b, u2, z4)));
        const float r  = fast_rcp(1.0f + exp2h(z));      // ONE exp2 + ONE rcp for all gates
        const float gt = fmaf(gA, r, gB);                // sigmoid / pre-scaled tanh
        const float iV = dppmv<DPP_SHR6>(gt);            // i: lanes 0..2  -> 6..8
        const float fV = dppmv<DPP_SHR3>(gt);            // f: lanes 3..5  -> 6..8
        const float oV = dppmv<DPP_SHL3>(gt);            // o: lanes 9..11 -> 6..8
        cs = fmaf(fV, cs, iV * gt);                      // g-lanes: gt = -2*L2E*g
        const float th = fmaf(2.0f, fast_rcp(1.0f + exp2h(cs)), -1.0f);  // tanh(c)
        const float h  = oV * th;                        // h_m on lane 6+m
        h0b = dppmv<DPP_NB6>(h);                         // VALU row-broadcast (was ds_swizzle)
        h1b = dppmv<DPP_NB7>(h);
        h2b = dppmv<DPP_NB8>(h);
    };

    auto scan32 = [&](const float* zb) {
        const float* zp = zb + e16 * ESTR + n;
        float pf[8];
        #pragma unroll
        for (int i = 0; i < 8; ++i) pf[i] = zp[i * TSTR];
        __builtin_amdgcn_s_setprio(1);
        #pragma unroll
        for (int tt = 0; tt < TCH; ++tt) {               // static unroll -> pf in regs
            const float z4 = pf[tt & 7];
            if (tt + 8 < TCH) pf[tt & 7] = zp[(tt + 8) * TSTR];
            comp(z4);
        }
        __builtin_amdgcn_s_setprio(0);
    };

    // ---- staging (wv2-3 only): issue-early global loads, convert+write bf16 A-frags ----
    float4 v[PPT];
    const int stid = tid - 128;             // 0..127 for wv2-3
    auto stage_issue = [&](int ck) {
        const int t0 = ck * TCH;
        #pragma unroll
        for (int i = 0; i < PPT; ++i) {
            const int piece = i * NSTG + stid;
            const int row = piece >> 4, g = piece & 15;
            v[i] = *reinterpret_cast<const float4*>(
                x + ((size_t)(b0 + (row >> 5)) * T_SZ + (t0 + (row & 31))) * F_SZ + (g << 2));
        }
    };
    auto stage_write = [&](int buf) {
        #pragma unroll
        for (int i = 0; i < PPT; ++i) {
            const int piece = i * NSTG + stid;
            const int row = piece >> 4, g = piece & 15;
            const int u_off = ((row >> 4) * 2 + (g >> 3)) * 256
                            + (((row & 15) | ((g & 3) << 4)) << 2) + ((g >> 2) & 1) * 2;
            uint2 pk;
            pk.x = (unsigned)f2bf(v[i].x) | ((unsigned)f2bf(v[i].y) << 16);
            pk.y = (unsigned)f2bf(v[i].z) | ((unsigned)f2bf(v[i].w) << 16);
            *reinterpret_cast<uint2*>(&xfrag[buf][u_off]) = pk;
        }
    };

    auto mfma_chunk = [&](int cur) {
        #pragma unroll
        for (int mt = 0; mt < MT; ++mt) {
            f32x4 acc = { bias_s, bias_s, bias_s, bias_s };
            const short8 a0 = *reinterpret_cast<const short8*>(&xfrag[cur][(mt * 2 + 0) * 256 + (ln << 2)]);
            const short8 a1 = *reinterpret_cast<const short8*>(&xfrag[cur][(mt * 2 + 1) * 256 + (ln << 2)]);
            acc = __builtin_amdgcn_mfma_f32_16x16x32_bf16(a0, bfrag[0], acc, 0, 0, 0);
            acc = __builtin_amdgcn_mfma_f32_16x16x32_bf16(a1, bfrag[1], acc, 0, 0, 0);
            const int rbase = mt * 16 + 4 * (ln >> 4);
            #pragma unroll
            for (int r = 0; r < 4; ++r) {
                const int rr = rbase + r;                 // row = b*32 + t
                zbuf[cur][(rr & 31) * TSTR + (rr >> 5) * ESTR + n] = acc[r];
            }
        }
    };

    // ---- prologue: staging waves fill chunk 0 ----
    if (wv >= 2) { stage_issue(0); stage_write(0); }
    __syncthreads();

    // ---- pipeline: staging(k+1) || mfma z(k) || scan(k-1), one barrier/chunk ----
    for (int k = 0; k < NCHK; ++k) {
        const int cur = k & 1;
        if (wv >= 2) {
            if (k + 1 < NCHK) { stage_issue(k + 1); stage_write(cur ^ 1); }
        } else if (wv == 1) {
            mfma_chunk(cur);
        } else if (k > 0) {
            scan32(zbuf[cur ^ 1]);
        }
        __syncthreads();
    }

    // ---- epilogue: scan last chunk + dense head ----
    if (wv == 0) {
        scan32(zbuf[(NCHK - 1) & 1]);
        if (n == 0) {   // one lane per element; h broadcasts hold h0,h1,h2
            const float logit = bdp[0] + h0b * Wd[0] + h1b * Wd[1] + h2b * Wd[2];
            out[b0 + e16] = sigm_n(logit);
        }
    }
}

extern "C" void kernel_launch(void* const* d_in, const int* in_sizes, int n_in,
                              void* d_out, int out_size, void* d_ws, size_t ws_size,
                              hipStream_t stream) {
    (void)in_sizes; (void)n_in; (void)out_size; (void)d_ws; (void)ws_size;
    const float* x  = (const float*)d_in[0];
    const float* W  = (const float*)d_in[1];
    const float* U  = (const float*)d_in[2];
    const float* b  = (const float*)d_in[3];
    const float* Wd = (const float*)d_in[4];
    const float* bd = (const float*)d_in[5];
    float* out = (float*)d_out;

    lstm_mfma<<<NBLK, NTHR, 0, stream>>>(x, W, U, b, Wd, bd, out);
}

// Round 17
// 54.042 us; speedup vs baseline: 4.9882x; 1.0027x over previous
//
#include <hip/hip_runtime.h>
#include <hip/hip_bf16.h>
#include <cstdint>

#define B_SZ 2048
#define T_SZ 512
#define F_SZ 64
#define BPB  4              // batch rows per block
#define TCH  32             // timesteps per chunk
#define NCHK (T_SZ / TCH)   // 16
#define NBLK (B_SZ / BPB)   // 512 -> 2 blocks/CU
#define NTHR 256            // wv0 scan, wv1 MFMA, wv2-3 staging
#define ROWS (BPB * TCH)    // 128 rows (b,t) per chunk
#define MT   (ROWS / 16)    // 8 M-tiles
#define NPC  (ROWS * 16)    // 2048 float4 staging pieces per chunk
#define NSTG 128            // staging threads (wv2+wv3)
#define PPT  (NPC / NSTG)   // 16 pieces per staging thread
#define TSTR 84             // zbuf t-stride (floats)
#define ESTR 20             // zbuf b-elem stride (floats)

#define L2E 1.4426950408889634f

typedef __attribute__((ext_vector_type(8))) short short8;
typedef __attribute__((ext_vector_type(4))) float f32x4;

__device__ __forceinline__ float fast_rcp(float x) { return __builtin_amdgcn_rcpf(x); }
__device__ __forceinline__ float exp2h(float x)    { return __builtin_amdgcn_exp2f(x); }
__device__ __forceinline__ float sigm_s(float zs)  { return fast_rcp(1.0f + exp2h(zs)); }
__device__ __forceinline__ float sigm_n(float x)   { return sigm_s(x * (-L2E)); }

__device__ __forceinline__ unsigned short f2bf(float f) {
    __hip_bfloat16 h = (__hip_bfloat16)f;   // RNE
    return *reinterpret_cast<unsigned short*>(&h);
}

template<int CTRL>
__device__ __forceinline__ float dppmv(float v) {
    return __int_as_float(__builtin_amdgcn_mov_dpp(__float_as_int(v), CTRL, 0xF, 0xF, true));
}
// row_shr:N -> lane i reads lane i-N
#define DPP_SHR6 0x116   // i-gates: src lanes 0..2 -> dst 6..8
#define DPP_SHR3 0x113   // f-gates: src lanes 3..5 -> dst 6..8
// row_newbcast:N (0x150+N): broadcast row-lane N to all 16 lanes (VALU DPP)
#define DPP_NB6  0x156
#define DPP_NB7  0x157
#define DPP_NB8  0x158
#define DPP_NB9  0x159
#define DPP_NB10 0x15A
#define DPP_NB11 0x15B

__global__ __launch_bounds__(NTHR) void lstm_mfma(const float* __restrict__ x,
                                                  const float* __restrict__ W,
                                                  const float* __restrict__ U,
                                                  const float* __restrict__ bias,
                                                  const float* __restrict__ Wd,
                                                  const float* __restrict__ bdp,
                                                  float* __restrict__ out) {
    // A-fragment-ordered x (bf16): per (Mtile,Ktile): 64 lanes x 16B
    __shared__ unsigned int xfrag[2][MT * 2 * 256];   // 2 x 16 KB
    __shared__ float zbuf[2][TCH * TSTR];             // 2 x 10.75 KB

    const int tid = threadIdx.x;
    const int wv  = tid >> 6;
    const int ln  = tid & 63;
    const int b0  = blockIdx.x * BPB;

    // ---- gate mapping: MFMA col n = Keras gate col (q*3+m), q=n/3, m=n%3 ----
    const int n  = ln & 15;                 // 12 real gates + 4 pad
    const int q  = n / 3;                   // 0:i 1:f 2:g 3:o (n<12)
    const float scq = (q == 2) ? (-2.0f * L2E) : (-L2E);

    // ---- B-fragments: W stationary in VGPRs (wv1 only uses them) ----
    short8 bfrag[2];
    #pragma unroll
    for (int kt = 0; kt < 2; ++kt) {
        short8 s;
        #pragma unroll
        for (int e = 0; e < 8; ++e) {
            const int hh = e >> 2, j = e & 3;
            const int kk = kt * 32 + hh * 16 + 4 * (ln >> 4) + j;   // f index
            const float w = (n < 12 && wv == 1) ? W[kk * 12 + n] * scq : 0.0f;
            s[e] = (short)f2bf(w);
        }
        bfrag[kt] = s;
    }
    const float bias_s = (n < 12) ? bias[n] * scq : 0.0f;

    // ---- scan constants (wv0): lane n = gate col; element e16 = ln>>4 ----
    const int e16 = ln >> 4;                // batch elem 0..3
    float nu0 = 0.f, nu1 = 0.f, nu2 = 0.f;  // -u_j   (u_j = U[j,n]*scq)
    float du0 = 0.f, du1 = 0.f, du2 = 0.f;  // 2*u_j
    float gA = 0.f, gB = 0.f;               // g-lane: gt = gA*r1 + gB = -2*L2E*tanh(z_g)
    if (n < 12) {
        const float u0 = U[0 * 12 + n] * scq;
        const float u1 = U[1 * 12 + n] * scq;
        const float u2 = U[2 * 12 + n] * scq;
        nu0 = -u0; nu1 = -u1; nu2 = -u2;
        du0 = 2.0f * u0; du1 = 2.0f * u1; du2 = 2.0f * u2;
        if (q == 2) { gA = -4.0f * L2E; gB = 2.0f * L2E; }
    }
    // scan state: z = current pre-activation; cs = -2*L2E*c (g-lanes);
    // carry = z_next minus its xw term (chunk-boundary); o/t broadcasts for epilogue
    float zz = 0.f, cs = 0.f, carry = 0.f;
    float o0b = 0.f, o1b = 0.f, o2b = 0.f, t0b = 0.f, t1b = 0.f, t2b = 0.f;

    // one step: consumes state zz, produces zz(next) [mid] or carry [last]
    auto step = [&](float pfn, bool fold_xw) {
        const float e1 = exp2h(zz);
        const float r1 = fast_rcp(1.0f + e1);           // gates (sigmoid lanes: value = gate)
        const float iV = dppmv<DPP_SHR6>(r1);           // i -> g-lanes
        const float fV = dppmv<DPP_SHR3>(r1);           // f -> g-lanes
        const float gt = fmaf(gA, r1, gB);              // g-lanes: -2*L2E*g
        o0b = dppmv<DPP_NB9>(r1);                       // o_j broadcasts (off-chain)
        o1b = dppmv<DPP_NB10>(r1);
        o2b = dppmv<DPP_NB11>(r1);
        const float base = fmaf(o0b, nu0, fmaf(o1b, nu1, fmaf(o2b, nu2, fold_xw ? pfn : 0.0f)));
        const float A0 = o0b * du0;                     // off-chain muls
        const float A1 = o1b * du1;
        const float A2 = o2b * du2;
        cs = fmaf(fV, cs, iV * gt);
        const float e2 = exp2h(cs);
        const float r2 = fast_rcp(1.0f + e2);           // rcp_c ; tanh(c) = 2*r2 - 1
        t0b = dppmv<DPP_NB6>(r2);                       // rcp_c broadcasts
        t1b = dppmv<DPP_NB7>(r2);
        t2b = dppmv<DPP_NB8>(r2);
        const float zn = fmaf(t0b, A0, fmaf(t1b, A1, fmaf(t2b, A2, base)));
        if (fold_xw) zz = zn; else carry = zn;
    };

    auto scan32 = [&](const float* zb) {
        const float* zp = zb + e16 * ESTR + n;
        float pf[8];
        #pragma unroll
        for (int i = 0; i < 8; ++i) pf[i] = zp[i * TSTR];
        __builtin_amdgcn_s_setprio(1);
        zz = carry + pf[0];                              // first step's pre-activation
        #pragma unroll
        for (int tt = 0; tt < TCH; ++tt) {
            const float pfn = pf[(tt + 1) & 7];          // xw row tt+1 (unused at tt=TCH-1)
            if (tt + 8 < TCH) pf[tt & 7] = zp[(tt + 8) * TSTR];
            step(pfn, tt < TCH - 1);
        }
        __builtin_amdgcn_s_setprio(0);
    };

    // ---- staging (wv2-3 only): issue-early global loads, convert+write bf16 A-frags ----
    float4 v[PPT];
    const int stid = tid - 128;             // 0..127 for wv2-3
    auto stage_issue = [&](int ck) {
        const int t0 = ck * TCH;
        #pragma unroll
        for (int i = 0; i < PPT; ++i) {
            const int piece = i * NSTG + stid;
            const int row = piece >> 4, g = piece & 15;
            v[i] = *reinterpret_cast<const float4*>(
                x + ((size_t)(b0 + (row >> 5)) * T_SZ + (t0 + (row & 31))) * F_SZ + (g << 2));
        }
    };
    auto stage_write = [&](int buf) {
        #pragma unroll
        for (int i = 0; i < PPT; ++i) {
            const int piece = i * NSTG + stid;
            const int row = piece >> 4, g = piece & 15;
            const int u_off = ((row >> 4) * 2 + (g >> 3)) * 256
                            + (((row & 15) | ((g & 3) << 4)) << 2) + ((g >> 2) & 1) * 2;
            uint2 pk;
            pk.x = (unsigned)f2bf(v[i].x) | ((unsigned)f2bf(v[i].y) << 16);
            pk.y = (unsigned)f2bf(v[i].z) | ((unsigned)f2bf(v[i].w) << 16);
            *reinterpret_cast<uint2*>(&xfrag[buf][u_off]) = pk;
        }
    };

    auto mfma_chunk = [&](int cur) {
        #pragma unroll
        for (int mt = 0; mt < MT; ++mt) {
            f32x4 acc = { bias_s, bias_s, bias_s, bias_s };
            const short8 a0 = *reinterpret_cast<const short8*>(&xfrag[cur][(mt * 2 + 0) * 256 + (ln << 2)]);
            const short8 a1 = *reinterpret_cast<const short8*>(&xfrag[cur][(mt * 2 + 1) * 256 + (ln << 2)]);
            acc = __builtin_amdgcn_mfma_f32_16x16x32_bf16(a0, bfrag[0], acc, 0, 0, 0);
            acc = __builtin_amdgcn_mfma_f32_16x16x32_bf16(a1, bfrag[1], acc, 0, 0, 0);
            const int rbase = mt * 16 + 4 * (ln >> 4);
            #pragma unroll
            for (int r = 0; r < 4; ++r) {
                const int rr = rbase + r;                 // row = b*32 + t
                zbuf[cur][(rr & 31) * TSTR + (rr >> 5) * ESTR + n] = acc[r];
            }
        }
    };

    // ---- prologue: staging waves fill chunk 0 ----
    if (wv >= 2) { stage_issue(0); stage_write(0); }
    __syncthreads();

    // ---- pipeline: staging(k+1) || mfma z(k) || scan(k-1), one barrier/chunk ----
    for (int k = 0; k < NCHK; ++k) {
        const int cur = k & 1;
        if (wv >= 2) {
            if (k + 1 < NCHK) { stage_issue(k + 1); stage_write(cur ^ 1); }
        } else if (wv == 1) {
            mfma_chunk(cur);
        } else if (k > 0) {
            scan32(zbuf[cur ^ 1]);
        }
        __syncthreads();
    }

    // ---- epilogue: scan last chunk + dense head ----
    if (wv == 0) {
        scan32(zbuf[(NCHK - 1) & 1]);
        if (n == 0) {
            // h_j = o_j * tanh(c_j); tanh = 2*r2_j - 1 (t_jb broadcasts from final step)
            const float h0 = o0b * fmaf(2.0f, t0b, -1.0f);
            const float h1 = o1b * fmaf(2.0f, t1b, -1.0f);
            const float h2 = o2b * fmaf(2.0f, t2b, -1.0f);
            const float logit = bdp[0] + h0 * Wd[0] + h1 * Wd[1] + h2 * Wd[2];
            out[b0 + e16] = sigm_n(logit);
        }
    }
}

extern "C" void kernel_launch(void* const* d_in, const int* in_sizes, int n_in,
                              void* d_out, int out_size, void* d_ws, size_t ws_size,
                              hipStream_t stream) {
    (void)in_sizes; (void)n_in; (void)out_size; (void)d_ws; (void)ws_size;
    const float* x  = (const float*)d_in[0];
    const float* W  = (const float*)d_in[1];
    const float* U  = (const float*)d_in[2];
    const float* b  = (const float*)d_in[3];
    const float* Wd = (const float*)d_in[4];
    const float* bd = (const float*)d_in[5];
    float* out = (float*)d_out;

    lstm_mfma<<<NBLK, NTHR, 0, stream>>>(x, W, U, b, Wd, bd, out);
}